// Round 4
// baseline (389.814 us; speedup 1.0000x reference)
//
#include <hip/hip_runtime.h>

#define NNODE 8192
#define NEDGE 4096
#define NCH   256
#define EPSV  1e-6f

typedef float  f32x4  __attribute__((ext_vector_type(4)));
typedef short  bf16x8 __attribute__((ext_vector_type(8)));
typedef unsigned short u16;
typedef unsigned int   u32;

static __device__ __forceinline__ u16 f2bf(float f) {
  union { float f; u32 u; } c; c.f = f;
  return (u16)((c.u + 0x7FFFu + ((c.u >> 16) & 1u)) >> 16);  // RNE
}

// async global->LDS, 16 B per lane; LDS dest is wave-uniform base + lane*16
static __device__ __forceinline__ void gload16(const u16* g, u16* l) {
  __builtin_amdgcn_global_load_lds((const __attribute__((address_space(1))) void*)g,
                                   (__attribute__((address_space(3))) void*)l,
                                   16, 0, 0);
}

// ---------------------------------------------------------------------------
// prep_h: 64x64 tile/block, 256 threads; thread t: a=t>>4 rows 4a..4a+3,
// b=t&15 cols 4b..4b+3. Hb from regs; HbT via uint2-packed LDS transpose;
// row sums via shfl; col sums via padded f32 partials. grid (128, 64).
// ---------------------------------------------------------------------------
__global__ __launch_bounds__(256) void prep_h(const float* __restrict__ H,
                                              u16* __restrict__ Hb,
                                              u16* __restrict__ HbT,
                                              float* __restrict__ d_v,
                                              float* __restrict__ d_e) {
  __shared__ uint2 Tp[64][17];   // [col][rowgroup] 4 rows packed bf16
  __shared__ float csp[16][68];  // [rowgroup][col] col partials
  __shared__ float rsum[64];
  const int t = threadIdx.x, a = t >> 4, b = t & 15;
  const int r0 = blockIdx.x * 64, c0 = blockIdx.y * 64;

  float4 v[4];
  #pragma unroll
  for (int i = 0; i < 4; ++i)
    v[i] = *(const float4*)&H[(size_t)(r0 + 4 * a + i) * NEDGE + c0 + 4 * b];

  #pragma unroll
  for (int i = 0; i < 4; ++i) {
    float rp = v[i].x + v[i].y + v[i].z + v[i].w;
    rp += __shfl_xor(rp, 1); rp += __shfl_xor(rp, 2);
    rp += __shfl_xor(rp, 4); rp += __shfl_xor(rp, 8);
    if (b == 0) rsum[4 * a + i] = rp;
  }
  csp[a][4 * b + 0] = v[0].x + v[1].x + v[2].x + v[3].x;
  csp[a][4 * b + 1] = v[0].y + v[1].y + v[2].y + v[3].y;
  csp[a][4 * b + 2] = v[0].z + v[1].z + v[2].z + v[3].z;
  csp[a][4 * b + 3] = v[0].w + v[1].w + v[2].w + v[3].w;

  u16 e[4][4];
  #pragma unroll
  for (int i = 0; i < 4; ++i) {
    e[i][0] = f2bf(v[i].x); e[i][1] = f2bf(v[i].y);
    e[i][2] = f2bf(v[i].z); e[i][3] = f2bf(v[i].w);
  }
  #pragma unroll
  for (int i = 0; i < 4; ++i) {
    uint2 hv;
    hv.x = (u32)e[i][0] | ((u32)e[i][1] << 16);
    hv.y = (u32)e[i][2] | ((u32)e[i][3] << 16);
    *(uint2*)&Hb[(size_t)(r0 + 4 * a + i) * NEDGE + c0 + 4 * b] = hv;
  }
  #pragma unroll
  for (int j = 0; j < 4; ++j) {
    uint2 tv;
    tv.x = (u32)e[0][j] | ((u32)e[1][j] << 16);
    tv.y = (u32)e[2][j] | ((u32)e[3][j] << 16);
    Tp[4 * b + j][a] = tv;
  }
  __syncthreads();

  #pragma unroll
  for (int s = 0; s < 2; ++s) {
    const int idx = t + 256 * s;
    const int c = idx >> 3, g = idx & 7;
    const uint2 p0 = Tp[c][2 * g], p1 = Tp[c][2 * g + 1];
    uint4 w; w.x = p0.x; w.y = p0.y; w.z = p1.x; w.w = p1.y;
    *(uint4*)&HbT[(size_t)(c0 + c) * NNODE + r0 + 8 * g] = w;
  }
  if (t < 64) {
    float s = 0.f;
    #pragma unroll
    for (int r = 0; r < 16; ++r) s += csp[r][t];
    atomicAdd(&d_e[c0 + t], s);
    atomicAdd(&d_v[r0 + t], rsum[t]);
  }
}

// ---------------------------------------------------------------------------
// prep_x: xsT[c][n] = bf16(x[n][c]*rsqrt(dv[n]+eps)); same transpose scheme.
// grid (NNODE/64=128, NCH/64=4)
// ---------------------------------------------------------------------------
__global__ __launch_bounds__(256) void prep_x(const float* __restrict__ x,
                                              const float* __restrict__ d_v,
                                              u16* __restrict__ xsT) {
  __shared__ uint2 Tp[64][17];
  const int t = threadIdx.x, a = t >> 4, b = t & 15;
  const int r0 = blockIdx.x * 64, c0 = blockIdx.y * 64;

  u16 e[4][4];
  #pragma unroll
  for (int i = 0; i < 4; ++i) {
    const int n = r0 + 4 * a + i;
    const float s = rsqrtf(d_v[n] + EPSV);
    const float4 v = *(const float4*)&x[(size_t)n * NCH + c0 + 4 * b];
    e[i][0] = f2bf(v.x * s); e[i][1] = f2bf(v.y * s);
    e[i][2] = f2bf(v.z * s); e[i][3] = f2bf(v.w * s);
  }
  #pragma unroll
  for (int j = 0; j < 4; ++j) {
    uint2 tv;
    tv.x = (u32)e[0][j] | ((u32)e[1][j] << 16);
    tv.y = (u32)e[2][j] | ((u32)e[3][j] << 16);
    Tp[4 * b + j][a] = tv;
  }
  __syncthreads();
  #pragma unroll
  for (int s = 0; s < 2; ++s) {
    const int idx = t + 256 * s;
    const int c = idx >> 3, g = idx & 7;
    const uint2 p0 = Tp[c][2 * g], p1 = Tp[c][2 * g + 1];
    uint4 w; w.x = p0.x; w.y = p0.y; w.z = p1.x; w.w = p1.y;
    *(uint4*)&xsT[(size_t)(c0 + c) * NNODE + r0 + 8 * g] = w;
  }
}

__global__ __launch_bounds__(256) void prep_w(const float* __restrict__ W,
                                              u16* __restrict__ Wb) {
  const int i = (blockIdx.x * 256 + threadIdx.x) * 8;
  const float4 a = *(const float4*)&W[i];
  const float4 b = *(const float4*)&W[i + 4];
  uint4 v;
  v.x = (u32)f2bf(a.x) | ((u32)f2bf(a.y) << 16);
  v.y = (u32)f2bf(a.z) | ((u32)f2bf(a.w) << 16);
  v.z = (u32)f2bf(b.x) | ((u32)f2bf(b.y) << 16);
  v.w = (u32)f2bf(b.z) | ((u32)f2bf(b.w) << 16);
  *(uint4*)&Wb[i] = v;
}

// init_out: out[n][o] = b[o]
__global__ __launch_bounds__(256) void init_out(const float* __restrict__ b,
                                                float* __restrict__ out) {
  const int i = (blockIdx.x * 256 + threadIdx.x) * 4;
  const float4 bb = *(const float4*)&b[i & 255];
  *(float4*)&out[i] = bb;
}

// ---------------------------------------------------------------------------
// staging helpers (XOR-swizzled via pre-swizzled global source, linear LDS)
// ---------------------------------------------------------------------------
template <int ROWS, int NT>
static __device__ __forceinline__ void stage_gl(const u16* __restrict__ base,
                                                int row0, int K, int kt,
                                                u16* lds, int tid) {
  const int w = tid >> 6, l = tid & 63;
  #pragma unroll
  for (int i = 0; i < (ROWS * 8) / NT; ++i) {
    const int slot = i * NT + w * 64 + l;
    const int row = slot >> 3, ch = slot & 7;
    const int sch = ch ^ (row & 7);
    gload16(base + (size_t)(row0 + row) * K + kt + sch * 8,
            lds + (size_t)(i * NT + w * 64) * 8);
  }
}

template <int ROWS, int NT>
static __device__ __forceinline__ void stage_f32(const float* __restrict__ base,
                                                 int row0, int K, int kt,
                                                 const float* __restrict__ sv,
                                                 u16* lds, int tid) {
  for (int idx = tid; idx < ROWS * 8; idx += NT) {
    const int row = idx >> 3, ch = idx & 7;
    const float s = 1.0f / (sv[row0 + row] + EPSV);
    const size_t g = (size_t)(row0 + row) * K + kt + ch * 8;
    const float4 v0 = *(const float4*)&base[g];
    const float4 v1 = *(const float4*)&base[g + 4];
    uint4 pv;
    pv.x = (u32)f2bf(v0.x * s) | ((u32)f2bf(v0.y * s) << 16);
    pv.y = (u32)f2bf(v0.z * s) | ((u32)f2bf(v0.w * s) << 16);
    pv.z = (u32)f2bf(v1.x * s) | ((u32)f2bf(v1.y * s) << 16);
    pv.w = (u32)f2bf(v1.z * s) | ((u32)f2bf(v1.w * s) << 16);
    *(uint4*)&lds[row * 64 + ((ch ^ (row & 7)) * 8)] = pv;
  }
}

// ---------------------------------------------------------------------------
// NT GEMM, split-K: C[m][n] = sum_k A[m][k]*B[n][k], bf16 MFMA 16x16x32.
// A bf16 gload_lds. BSRC: 0 = B bf16 gload_lds; 1 = B f32 reg-staged,
// row-scaled by 1/(svb[row]+eps). EPI: 0 atomicAdd f32; 1 atomicAdd f32 *
// rsqrt(sve[row]+eps); 2 plain bf16 store. XCD-chunked block swizzle.
// ---------------------------------------------------------------------------
template <int BM, int BN, int WM, int WN, int BSRC, int EPI>
__global__ __launch_bounds__(WM * WN * 64) void gemm_nt(
    const u16* __restrict__ Aptr, const void* __restrict__ Bptr,
    int K, int KC,
    const float* __restrict__ svb, const float* __restrict__ sve,
    void* __restrict__ Cout, int ldc) {
  constexpr int BK = 64;
  constexpr int NT = WM * WN * 64;
  constexpr int WMR = BM / WM, WNR = BN / WN;
  constexpr int FM = WMR / 16, FN = WNR / 16;
  __shared__ u16 lds_a[BM * BK];
  __shared__ u16 lds_b[BN * BK];

  const int tid  = threadIdx.x;
  const int lane = tid & 63;
  const int w    = tid >> 6;
  const int wm   = w / WN, wn = w % WN;

  // XCD-chunked swizzle (bijective when nwg%8==0)
  const int nx = gridDim.x, ny = gridDim.y;
  const int nwg = nx * ny * gridDim.z;
  int lid = blockIdx.x + nx * (blockIdx.y + ny * blockIdx.z);
  if ((nwg & 7) == 0) lid = (lid & 7) * (nwg >> 3) + (lid >> 3);
  const int bx = lid % nx;
  const int byz = lid / nx;
  const int by = byz % ny, bz = byz / ny;

  const int m0 = bx * BM;
  const int n0 = by * BN;
  const int k0 = bz * KC;

  f32x4 acc[FM][FN];
  #pragma unroll
  for (int fm = 0; fm < FM; ++fm)
    #pragma unroll
    for (int fn = 0; fn < FN; ++fn)
      acc[fm][fn] = (f32x4){0.f, 0.f, 0.f, 0.f};

  for (int kt = k0; kt < k0 + KC; kt += BK) {
    __syncthreads();
    stage_gl<BM, NT>(Aptr, m0, K, kt, lds_a, tid);
    if constexpr (BSRC == 0) {
      stage_gl<BN, NT>((const u16*)Bptr, n0, K, kt, lds_b, tid);
    } else {
      stage_f32<BN, NT>((const float*)Bptr, n0, K, kt, svb, lds_b, tid);
    }
    __syncthreads();

    #pragma unroll
    for (int kk = 0; kk < 2; ++kk) {
      bf16x8 af[FM], bfv[FN];
      #pragma unroll
      for (int fm = 0; fm < FM; ++fm) {
        const int row = wm * WMR + fm * 16 + (lane & 15);
        const int ch  = kk * 4 + (lane >> 4);
        af[fm] = *(const bf16x8*)&lds_a[row * BK + ((ch ^ (row & 7)) * 8)];
      }
      #pragma unroll
      for (int fn = 0; fn < FN; ++fn) {
        const int row = wn * WNR + fn * 16 + (lane & 15);
        const int ch  = kk * 4 + (lane >> 4);
        bfv[fn] = *(const bf16x8*)&lds_b[row * BK + ((ch ^ (row & 7)) * 8)];
      }
      #pragma unroll
      for (int fm = 0; fm < FM; ++fm)
        #pragma unroll
        for (int fn = 0; fn < FN; ++fn)
          acc[fm][fn] = __builtin_amdgcn_mfma_f32_16x16x32_bf16(
              af[fm], bfv[fn], acc[fm][fn], 0, 0, 0);
    }
  }

  if constexpr (EPI == 0) {
    float* C = (float*)Cout;
    #pragma unroll
    for (int fm = 0; fm < FM; ++fm) {
      const int rowb = m0 + wm * WMR + fm * 16 + ((lane >> 4) << 2);
      #pragma unroll
      for (int fn = 0; fn < FN; ++fn) {
        const int col = n0 + wn * WNR + fn * 16 + (lane & 15);
        #pragma unroll
        for (int r = 0; r < 4; ++r)
          atomicAdd(&C[(size_t)(rowb + r) * ldc + col], acc[fm][fn][r]);
      }
    }
  } else if constexpr (EPI == 1) {
    float* C = (float*)Cout;
    #pragma unroll
    for (int fm = 0; fm < FM; ++fm) {
      const int rowb = m0 + wm * WMR + fm * 16 + ((lane >> 4) << 2);
      float s[4];
      #pragma unroll
      for (int r = 0; r < 4; ++r) s[r] = rsqrtf(sve[rowb + r] + EPSV);
      #pragma unroll
      for (int fn = 0; fn < FN; ++fn) {
        const int col = n0 + wn * WNR + fn * 16 + (lane & 15);
        #pragma unroll
        for (int r = 0; r < 4; ++r)
          atomicAdd(&C[(size_t)(rowb + r) * ldc + col], acc[fm][fn][r] * s[r]);
      }
    }
  } else {
    u16* C = (u16*)Cout;
    #pragma unroll
    for (int fm = 0; fm < FM; ++fm) {
      const int rowb = m0 + wm * WMR + fm * 16 + ((lane >> 4) << 2);
      #pragma unroll
      for (int fn = 0; fn < FN; ++fn) {
        const int col = n0 + wn * WNR + fn * 16 + (lane & 15);
        #pragma unroll
        for (int r = 0; r < 4; ++r)
          C[(size_t)(rowb + r) * ldc + col] = f2bf(acc[fm][fn][r]);
      }
    }
  }
}

// ---------------------------------------------------------------------------
extern "C" void kernel_launch(void* const* d_in, const int* in_sizes, int n_in,
                              void* d_out, int out_size, void* d_ws, size_t ws_size,
                              hipStream_t stream) {
  const float* x = (const float*)d_in[0];   // [8192][256]
  const float* H = (const float*)d_in[1];   // [8192][4096]
  const float* W = (const float*)d_in[2];   // [256][256]
  const float* b = (const float*)d_in[3];   // [256]
  float* out = (float*)d_out;               // [8192][256] f32

  char* ws = (char*)d_ws;
  u16*   HbT  = (u16*)(ws);                          // 64 MiB  [E][N] bf16
  u16*   Hb   = (u16*)(ws + 67108864ull);            // 64 MiB  [N][E] bf16
  u16*   xsT  = (u16*)(ws + 134217728ull);           //  4 MiB  [C][N] bf16
  float* tAcc = (float*)(ws + 138412032ull);         //  4 MiB  [E][C] f32
  u16*   uT   = (u16*)(ws + 142606336ull);           //  2 MiB  [O][E] bf16
  u16*   Wb   = (u16*)(ws + 144703488ull);           // 128 KiB [O][C] bf16
  float* dv   = (float*)(ws + 144834560ull);         // 32 KiB
  float* de   = (float*)(ws + 144867328ull);         // 16 KiB

  hipMemsetAsync(dv, 0, (NNODE + NEDGE) * sizeof(float), stream);
  hipMemsetAsync(tAcc, 0, (size_t)NEDGE * NCH * sizeof(float), stream);

  prep_h<<<dim3(NNODE / 64, NEDGE / 64), 256, 0, stream>>>(H, Hb, HbT, dv, de);
  prep_x<<<dim3(NNODE / 64, NCH / 64), 256, 0, stream>>>(x, dv, xsT);
  prep_w<<<32, 256, 0, stream>>>(W, Wb);
  init_out<<<(NNODE * NCH) / 1024, 256, 0, stream>>>(b, out);

  // GEMM1: tAcc[e][c] += sum_n HbT[e][n]*xsT[c][n]   (split-K S=16)
  gemm_nt<128, 128, 2, 2, 0, 0><<<dim3(NEDGE / 128, NCH / 128, 16), 256, 0, stream>>>(
      HbT, xsT, NNODE, NNODE / 16, nullptr, nullptr, tAcc, NCH);
  // GEMM-W: uT[o][e] = sum_c Wb[o][c] * (de_inv[e]*tAcc[e][c])
  gemm_nt<64, 128, 2, 2, 1, 2><<<dim3(4, NEDGE / 128, 1), 256, 0, stream>>>(
      Wb, tAcc, NCH, NCH, de, nullptr, uT, NEDGE);
  // GEMM2: out[n][o] += rsqrt(dv[n]) * sum_e Hb[n][e]*uT[o][e]  (split-K S=8)
  gemm_nt<128, 128, 2, 2, 0, 1><<<dim3(NNODE / 128, NCH / 128, 8), 256, 0, stream>>>(
      Hb, uT, NEDGE, NEDGE / 8, nullptr, dv, out, NCH);
}

// Round 5
// 379.176 us; speedup vs baseline: 1.0281x; 1.0281x over previous
//
#include <hip/hip_runtime.h>

#define NNODE 8192
#define NEDGE 4096
#define NCH   256
#define EPSV  1e-6f

typedef float  f32x4  __attribute__((ext_vector_type(4)));
typedef short  bf16x8 __attribute__((ext_vector_type(8)));
typedef unsigned short u16;
typedef unsigned int   u32;

static __device__ __forceinline__ u16 f2bf(float f) {
  union { float f; u32 u; } c; c.f = f;
  return (u16)((c.u + 0x7FFFu + ((c.u >> 16) & 1u)) >> 16);  // RNE
}

// async global->LDS, 16 B per lane; LDS dest is wave-uniform base + lane*16
static __device__ __forceinline__ void gload16(const u16* g, u16* l) {
  __builtin_amdgcn_global_load_lds((const __attribute__((address_space(1))) void*)g,
                                   (__attribute__((address_space(3))) void*)l,
                                   16, 0, 0);
}

static __device__ __forceinline__ uint4 pack8(const float4& a, const float4& c) {
  uint4 v;
  v.x = (u32)f2bf(a.x) | ((u32)f2bf(a.y) << 16);
  v.y = (u32)f2bf(a.z) | ((u32)f2bf(a.w) << 16);
  v.z = (u32)f2bf(c.x) | ((u32)f2bf(c.y) << 16);
  v.w = (u32)f2bf(c.z) | ((u32)f2bf(c.w) << 16);
  return v;
}

// ---------------------------------------------------------------------------
// prep_h: 64x64 tile/block. Degrees (shfl rows, padded-partial cols) +
// HbT[e][n] bf16 via f32 b128 LDS transpose (write T[c][4a..4a+3] b128,
// read T[c][8g..8g+7] b128 — uniform bank coverage). No Hb output.
// grid (NNODE/64=128, NEDGE/64=64), 256 threads.
// ---------------------------------------------------------------------------
__global__ __launch_bounds__(256) void prep_h(const float* __restrict__ H,
                                              u16* __restrict__ HbT,
                                              float* __restrict__ d_v,
                                              float* __restrict__ d_e) {
  __shared__ float T[64][68];    // [col e][row n] f32
  __shared__ float csp[16][68];  // col partials
  __shared__ float rsum[64];
  const int t = threadIdx.x, a = t >> 4, b = t & 15;
  const int r0 = blockIdx.x * 64, c0 = blockIdx.y * 64;

  float4 v[4];
  #pragma unroll
  for (int i = 0; i < 4; ++i)
    v[i] = *(const float4*)&H[(size_t)(r0 + 4 * a + i) * NEDGE + c0 + 4 * b];

  #pragma unroll
  for (int i = 0; i < 4; ++i) {
    float rp = v[i].x + v[i].y + v[i].z + v[i].w;
    rp += __shfl_xor(rp, 1); rp += __shfl_xor(rp, 2);
    rp += __shfl_xor(rp, 4); rp += __shfl_xor(rp, 8);
    if (b == 0) rsum[4 * a + i] = rp;
  }
  csp[a][4 * b + 0] = v[0].x + v[1].x + v[2].x + v[3].x;
  csp[a][4 * b + 1] = v[0].y + v[1].y + v[2].y + v[3].y;
  csp[a][4 * b + 2] = v[0].z + v[1].z + v[2].z + v[3].z;
  csp[a][4 * b + 3] = v[0].w + v[1].w + v[2].w + v[3].w;

  // transposed f32 stage: T[col][row], one b128 per col j
  {
    float4 w0 = {v[0].x, v[1].x, v[2].x, v[3].x};
    float4 w1 = {v[0].y, v[1].y, v[2].y, v[3].y};
    float4 w2 = {v[0].z, v[1].z, v[2].z, v[3].z};
    float4 w3 = {v[0].w, v[1].w, v[2].w, v[3].w};
    *(float4*)&T[4 * b + 0][4 * a] = w0;
    *(float4*)&T[4 * b + 1][4 * a] = w1;
    *(float4*)&T[4 * b + 2][4 * a] = w2;
    *(float4*)&T[4 * b + 3][4 * a] = w3;
  }
  __syncthreads();

  #pragma unroll
  for (int s = 0; s < 2; ++s) {
    const int idx = t + 256 * s;
    const int c = idx >> 3, g = idx & 7;
    const float4 p0 = *(const float4*)&T[c][8 * g];
    const float4 p1 = *(const float4*)&T[c][8 * g + 4];
    *(uint4*)&HbT[(size_t)(c0 + c) * NNODE + r0 + 8 * g] = pack8(p0, p1);
  }
  if (t < 64) {
    float s = 0.f;
    #pragma unroll
    for (int r = 0; r < 16; ++r) s += csp[r][t];
    atomicAdd(&d_e[c0 + t], s);
    atomicAdd(&d_v[r0 + t], rsum[t]);
  }
}

// ---------------------------------------------------------------------------
// prep_x: xsT[c][n] = bf16(x[n][c]*rsqrt(dv[n]+eps)); same transpose scheme.
// grid (NNODE/64=128, NCH/64=4), 256 threads.
// ---------------------------------------------------------------------------
__global__ __launch_bounds__(256) void prep_x(const float* __restrict__ x,
                                              const float* __restrict__ d_v,
                                              u16* __restrict__ xsT) {
  __shared__ float T[64][68];
  const int t = threadIdx.x, a = t >> 4, b = t & 15;
  const int r0 = blockIdx.x * 64, c0 = blockIdx.y * 64;

  float4 v[4];
  #pragma unroll
  for (int i = 0; i < 4; ++i) {
    const int n = r0 + 4 * a + i;
    const float s = rsqrtf(d_v[n] + EPSV);
    float4 w = *(const float4*)&x[(size_t)n * NCH + c0 + 4 * b];
    w.x *= s; w.y *= s; w.z *= s; w.w *= s;
    v[i] = w;
  }
  {
    float4 w0 = {v[0].x, v[1].x, v[2].x, v[3].x};
    float4 w1 = {v[0].y, v[1].y, v[2].y, v[3].y};
    float4 w2 = {v[0].z, v[1].z, v[2].z, v[3].z};
    float4 w3 = {v[0].w, v[1].w, v[2].w, v[3].w};
    *(float4*)&T[4 * b + 0][4 * a] = w0;
    *(float4*)&T[4 * b + 1][4 * a] = w1;
    *(float4*)&T[4 * b + 2][4 * a] = w2;
    *(float4*)&T[4 * b + 3][4 * a] = w3;
  }
  __syncthreads();
  #pragma unroll
  for (int s = 0; s < 2; ++s) {
    const int idx = t + 256 * s;
    const int c = idx >> 3, g = idx & 7;
    const float4 p0 = *(const float4*)&T[c][8 * g];
    const float4 p1 = *(const float4*)&T[c][8 * g + 4];
    *(uint4*)&xsT[(size_t)(c0 + c) * NNODE + r0 + 8 * g] = pack8(p0, p1);
  }
}

__global__ __launch_bounds__(256) void prep_w(const float* __restrict__ W,
                                              u16* __restrict__ Wb) {
  const int i = (blockIdx.x * 256 + threadIdx.x) * 8;
  const float4 a = *(const float4*)&W[i];
  const float4 b = *(const float4*)&W[i + 4];
  *(uint4*)&Wb[i] = pack8(a, b);
}

// init_out: out[n][o] = b[o]
__global__ __launch_bounds__(256) void init_out(const float* __restrict__ b,
                                                float* __restrict__ out) {
  const int i = (blockIdx.x * 256 + threadIdx.x) * 4;
  const float4 bb = *(const float4*)&b[i & 255];
  *(float4*)&out[i] = bb;
}

// ---------------------------------------------------------------------------
// staging helpers (XOR-swizzled via pre-swizzled global source, linear LDS)
// ---------------------------------------------------------------------------
template <int ROWS, int NT>
static __device__ __forceinline__ void stage_gl(const u16* __restrict__ base,
                                                int row0, int K, int kt,
                                                u16* lds, int tid) {
  const int w = tid >> 6, l = tid & 63;
  #pragma unroll
  for (int i = 0; i < (ROWS * 8) / NT; ++i) {
    const int slot = i * NT + w * 64 + l;
    const int row = slot >> 3, ch = slot & 7;
    const int sch = ch ^ (row & 7);
    gload16(base + (size_t)(row0 + row) * K + kt + sch * 8,
            lds + (size_t)(i * NT + w * 64) * 8);
  }
}

// SCALE: 0 none, 1 multiply by 1/(sv[row]+eps)
template <int ROWS, int NT, int SCALE>
static __device__ __forceinline__ void stage_f32(const float* __restrict__ base,
                                                 int row0, int K, int kt,
                                                 const float* __restrict__ sv,
                                                 u16* lds, int tid) {
  for (int idx = tid; idx < ROWS * 8; idx += NT) {
    const int row = idx >> 3, ch = idx & 7;
    float s = 1.0f;
    if constexpr (SCALE == 1) s = 1.0f / (sv[row0 + row] + EPSV);
    const size_t g = (size_t)(row0 + row) * K + kt + ch * 8;
    float4 v0 = *(const float4*)&base[g];
    float4 v1 = *(const float4*)&base[g + 4];
    v0.x *= s; v0.y *= s; v0.z *= s; v0.w *= s;
    v1.x *= s; v1.y *= s; v1.z *= s; v1.w *= s;
    *(uint4*)&lds[row * 64 + ((ch ^ (row & 7)) * 8)] = pack8(v0, v1);
  }
}

// ---------------------------------------------------------------------------
// NT GEMM, split-K: C[m][n] = sum_k A[m][k]*B[n][k], bf16 MFMA 16x16x32.
// ASRC: 0 = A bf16 gload_lds; 1 = A f32 reg-staged (plain convert)
// BSRC: 0 = B bf16 gload_lds; 1 = B f32 reg-staged * 1/(svb[row]+eps)
// EPI : 0 = atomicAdd f32; 1 = atomicAdd f32 * rsqrt(sve[row]+eps);
//       2 = plain bf16 store
// No block swizzle (split-K atomics must stay C-disjoint across XCDs).
// ---------------------------------------------------------------------------
template <int BM, int BN, int WM, int WN, int ASRC, int BSRC, int EPI>
__global__ __launch_bounds__(WM * WN * 64, 4) void gemm_nt(
    const void* __restrict__ Aptr, const void* __restrict__ Bptr,
    int K, int KC,
    const float* __restrict__ svb, const float* __restrict__ sve,
    void* __restrict__ Cout, int ldc) {
  constexpr int BK = 64;
  constexpr int NT = WM * WN * 64;
  constexpr int WMR = BM / WM, WNR = BN / WN;
  constexpr int FM = WMR / 16, FN = WNR / 16;
  __shared__ u16 lds_a[BM * BK];
  __shared__ u16 lds_b[BN * BK];

  const int tid  = threadIdx.x;
  const int lane = tid & 63;
  const int w    = tid >> 6;
  const int wm   = w / WN, wn = w % WN;
  const int m0   = blockIdx.x * BM;
  const int n0   = blockIdx.y * BN;
  const int k0   = blockIdx.z * KC;

  f32x4 acc[FM][FN];
  #pragma unroll
  for (int fm = 0; fm < FM; ++fm)
    #pragma unroll
    for (int fn = 0; fn < FN; ++fn)
      acc[fm][fn] = (f32x4){0.f, 0.f, 0.f, 0.f};

  for (int kt = k0; kt < k0 + KC; kt += BK) {
    __syncthreads();
    if constexpr (ASRC == 0) {
      stage_gl<BM, NT>((const u16*)Aptr, m0, K, kt, lds_a, tid);
    } else {
      stage_f32<BM, NT, 0>((const float*)Aptr, m0, K, kt, nullptr, lds_a, tid);
    }
    if constexpr (BSRC == 0) {
      stage_gl<BN, NT>((const u16*)Bptr, n0, K, kt, lds_b, tid);
    } else {
      stage_f32<BN, NT, 1>((const float*)Bptr, n0, K, kt, svb, lds_b, tid);
    }
    __syncthreads();

    #pragma unroll
    for (int kk = 0; kk < 2; ++kk) {
      bf16x8 af[FM], bfv[FN];
      #pragma unroll
      for (int fm = 0; fm < FM; ++fm) {
        const int row = wm * WMR + fm * 16 + (lane & 15);
        const int ch  = kk * 4 + (lane >> 4);
        af[fm] = *(const bf16x8*)&lds_a[row * BK + ((ch ^ (row & 7)) * 8)];
      }
      #pragma unroll
      for (int fn = 0; fn < FN; ++fn) {
        const int row = wn * WNR + fn * 16 + (lane & 15);
        const int ch  = kk * 4 + (lane >> 4);
        bfv[fn] = *(const bf16x8*)&lds_b[row * BK + ((ch ^ (row & 7)) * 8)];
      }
      #pragma unroll
      for (int fm = 0; fm < FM; ++fm)
        #pragma unroll
        for (int fn = 0; fn < FN; ++fn)
          acc[fm][fn] = __builtin_amdgcn_mfma_f32_16x16x32_bf16(
              af[fm], bfv[fn], acc[fm][fn], 0, 0, 0);
    }
  }

  if constexpr (EPI == 0) {
    float* C = (float*)Cout;
    #pragma unroll
    for (int fm = 0; fm < FM; ++fm) {
      const int rowb = m0 + wm * WMR + fm * 16 + ((lane >> 4) << 2);
      #pragma unroll
      for (int fn = 0; fn < FN; ++fn) {
        const int col = n0 + wn * WNR + fn * 16 + (lane & 15);
        #pragma unroll
        for (int r = 0; r < 4; ++r)
          atomicAdd(&C[(size_t)(rowb + r) * ldc + col], acc[fm][fn][r]);
      }
    }
  } else if constexpr (EPI == 1) {
    float* C = (float*)Cout;
    #pragma unroll
    for (int fm = 0; fm < FM; ++fm) {
      const int rowb = m0 + wm * WMR + fm * 16 + ((lane >> 4) << 2);
      float s[4];
      #pragma unroll
      for (int r = 0; r < 4; ++r) s[r] = rsqrtf(sve[rowb + r] + EPSV);
      #pragma unroll
      for (int fn = 0; fn < FN; ++fn) {
        const int col = n0 + wn * WNR + fn * 16 + (lane & 15);
        #pragma unroll
        for (int r = 0; r < 4; ++r)
          atomicAdd(&C[(size_t)(rowb + r) * ldc + col], acc[fm][fn][r] * s[r]);
      }
    }
  } else {
    u16* C = (u16*)Cout;
    #pragma unroll
    for (int fm = 0; fm < FM; ++fm) {
      const int rowb = m0 + wm * WMR + fm * 16 + ((lane >> 4) << 2);
      #pragma unroll
      for (int fn = 0; fn < FN; ++fn) {
        const int col = n0 + wn * WNR + fn * 16 + (lane & 15);
        #pragma unroll
        for (int r = 0; r < 4; ++r)
          C[(size_t)(rowb + r) * ldc + col] = f2bf(acc[fm][fn][r]);
      }
    }
  }
}

// ---------------------------------------------------------------------------
extern "C" void kernel_launch(void* const* d_in, const int* in_sizes, int n_in,
                              void* d_out, int out_size, void* d_ws, size_t ws_size,
                              hipStream_t stream) {
  const float* x = (const float*)d_in[0];   // [8192][256]
  const float* H = (const float*)d_in[1];   // [8192][4096]
  const float* W = (const float*)d_in[2];   // [256][256]
  const float* b = (const float*)d_in[3];   // [256]
  float* out = (float*)d_out;               // [8192][256] f32

  char* ws = (char*)d_ws;
  u16*   HbT  = (u16*)(ws);                          // 64 MiB  [E][N] bf16
  u16*   xsT  = (u16*)(ws + 67108864ull);            //  4 MiB  [C][N] bf16
  float* tAcc = (float*)(ws + 71303168ull);          //  4 MiB  [E][C] f32
  u16*   uT   = (u16*)(ws + 75497472ull);            //  2 MiB  [O][E] bf16
  u16*   Wb   = (u16*)(ws + 77594624ull);            // 128 KiB [O][C] bf16
  float* dv   = (float*)(ws + 77725696ull);          // 32 KiB
  float* de   = (float*)(ws + 77758464ull);          // 16 KiB

  hipMemsetAsync(dv, 0, (NNODE + NEDGE) * sizeof(float), stream);
  hipMemsetAsync(tAcc, 0, (size_t)NEDGE * NCH * sizeof(float), stream);

  prep_h<<<dim3(NNODE / 64, NEDGE / 64), 256, 0, stream>>>(H, HbT, dv, de);
  prep_x<<<dim3(NNODE / 64, NCH / 64), 256, 0, stream>>>(x, dv, xsT);
  prep_w<<<32, 256, 0, stream>>>(W, Wb);
  init_out<<<(NNODE * NCH) / 1024, 256, 0, stream>>>(b, out);

  // GEMM1: tAcc[e][c] += sum_n HbT[e][n]*xsT[c][n]   (split-K S=16)
  gemm_nt<128, 256, 2, 4, 0, 0, 0><<<dim3(NEDGE / 128, 1, 16), 512, 0, stream>>>(
      HbT, xsT, NNODE, NNODE / 16, nullptr, nullptr, tAcc, NCH);
  // GEMM-W: uT[o][e] = sum_c Wb[o][c] * (de_inv[e]*tAcc[e][c])
  gemm_nt<64, 64, 2, 2, 0, 1, 2><<<dim3(4, NEDGE / 64, 1), 256, 0, stream>>>(
      Wb, tAcc, NCH, NCH, de, nullptr, uT, NEDGE);
  // GEMM2: out[n][o] += rsqrt(dv[n]+eps) * sum_e H[n][e]*uT[o][e]  (split-K S=8,
  // A = H f32 converted in staging, bias pre-initialized)
  gemm_nt<128, 256, 2, 4, 1, 0, 1><<<dim3(NNODE / 128, 1, 8), 512, 0, stream>>>(
      H, uT, NEDGE, NEDGE / 8, nullptr, dv, out, NCH);
}

// Round 7
// 315.612 us; speedup vs baseline: 1.2351x; 1.2014x over previous
//
#include <hip/hip_runtime.h>

#define NNODE 8192
#define NEDGE 4096
#define NCH   256
#define EPSV  1e-6f

typedef float  f32x4  __attribute__((ext_vector_type(4)));
typedef short  bf16x8 __attribute__((ext_vector_type(8)));
typedef unsigned short u16;
typedef unsigned int   u32;

static __device__ __forceinline__ u16 f2bf(float f) {
  union { float f; u32 u; } c; c.f = f;
  return (u16)((c.u + 0x7FFFu + ((c.u >> 16) & 1u)) >> 16);  // RNE
}

// async global->LDS, 16 B per lane; LDS dest is wave-uniform base + lane*16
static __device__ __forceinline__ void gload16(const u16* g, u16* l) {
  __builtin_amdgcn_global_load_lds((const __attribute__((address_space(1))) void*)g,
                                   (__attribute__((address_space(3))) void*)l,
                                   16, 0, 0);
}

static __device__ __forceinline__ uint4 pack8(const float4& a, const float4& c) {
  uint4 v;
  v.x = (u32)f2bf(a.x) | ((u32)f2bf(a.y) << 16);
  v.y = (u32)f2bf(a.z) | ((u32)f2bf(a.w) << 16);
  v.z = (u32)f2bf(c.x) | ((u32)f2bf(c.y) << 16);
  v.w = (u32)f2bf(c.z) | ((u32)f2bf(c.w) << 16);
  return v;
}

// ---------------------------------------------------------------------------
// prep_h: 64x64 tile/block. Degrees + HbT[e][n] bf16 via f32 b128 LDS
// transpose. grid (128, 64), 256 threads.
// ---------------------------------------------------------------------------
__global__ __launch_bounds__(256) void prep_h(const float* __restrict__ H,
                                              u16* __restrict__ HbT,
                                              float* __restrict__ d_v,
                                              float* __restrict__ d_e) {
  __shared__ float T[64][68];
  __shared__ float csp[16][68];
  __shared__ float rsum[64];
  const int t = threadIdx.x, a = t >> 4, b = t & 15;
  const int r0 = blockIdx.x * 64, c0 = blockIdx.y * 64;

  float4 v[4];
  #pragma unroll
  for (int i = 0; i < 4; ++i)
    v[i] = *(const float4*)&H[(size_t)(r0 + 4 * a + i) * NEDGE + c0 + 4 * b];

  #pragma unroll
  for (int i = 0; i < 4; ++i) {
    float rp = v[i].x + v[i].y + v[i].z + v[i].w;
    rp += __shfl_xor(rp, 1); rp += __shfl_xor(rp, 2);
    rp += __shfl_xor(rp, 4); rp += __shfl_xor(rp, 8);
    if (b == 0) rsum[4 * a + i] = rp;
  }
  csp[a][4 * b + 0] = v[0].x + v[1].x + v[2].x + v[3].x;
  csp[a][4 * b + 1] = v[0].y + v[1].y + v[2].y + v[3].y;
  csp[a][4 * b + 2] = v[0].z + v[1].z + v[2].z + v[3].z;
  csp[a][4 * b + 3] = v[0].w + v[1].w + v[2].w + v[3].w;

  {
    float4 w0 = {v[0].x, v[1].x, v[2].x, v[3].x};
    float4 w1 = {v[0].y, v[1].y, v[2].y, v[3].y};
    float4 w2 = {v[0].z, v[1].z, v[2].z, v[3].z};
    float4 w3 = {v[0].w, v[1].w, v[2].w, v[3].w};
    *(float4*)&T[4 * b + 0][4 * a] = w0;
    *(float4*)&T[4 * b + 1][4 * a] = w1;
    *(float4*)&T[4 * b + 2][4 * a] = w2;
    *(float4*)&T[4 * b + 3][4 * a] = w3;
  }
  __syncthreads();

  #pragma unroll
  for (int s = 0; s < 2; ++s) {
    const int idx = t + 256 * s;
    const int c = idx >> 3, g = idx & 7;
    const float4 p0 = *(const float4*)&T[c][8 * g];
    const float4 p1 = *(const float4*)&T[c][8 * g + 4];
    *(uint4*)&HbT[(size_t)(c0 + c) * NNODE + r0 + 8 * g] = pack8(p0, p1);
  }
  if (t < 64) {
    float s = 0.f;
    #pragma unroll
    for (int r = 0; r < 16; ++r) s += csp[r][t];
    atomicAdd(&d_e[c0 + t], s);
    atomicAdd(&d_v[r0 + t], rsum[t]);
  }
}

// ---------------------------------------------------------------------------
// prep_x: xsT[c][n] = bf16(x[n][c]*rsqrt(dv[n]+eps)); grid (128, 4).
// ---------------------------------------------------------------------------
__global__ __launch_bounds__(256) void prep_x(const float* __restrict__ x,
                                              const float* __restrict__ d_v,
                                              u16* __restrict__ xsT) {
  __shared__ float T[64][68];
  const int t = threadIdx.x, a = t >> 4, b = t & 15;
  const int r0 = blockIdx.x * 64, c0 = blockIdx.y * 64;

  float4 v[4];
  #pragma unroll
  for (int i = 0; i < 4; ++i) {
    const int n = r0 + 4 * a + i;
    const float s = rsqrtf(d_v[n] + EPSV);
    float4 w = *(const float4*)&x[(size_t)n * NCH + c0 + 4 * b];
    w.x *= s; w.y *= s; w.z *= s; w.w *= s;
    v[i] = w;
  }
  {
    float4 w0 = {v[0].x, v[1].x, v[2].x, v[3].x};
    float4 w1 = {v[0].y, v[1].y, v[2].y, v[3].y};
    float4 w2 = {v[0].z, v[1].z, v[2].z, v[3].z};
    float4 w3 = {v[0].w, v[1].w, v[2].w, v[3].w};
    *(float4*)&T[4 * b + 0][4 * a] = w0;
    *(float4*)&T[4 * b + 1][4 * a] = w1;
    *(float4*)&T[4 * b + 2][4 * a] = w2;
    *(float4*)&T[4 * b + 3][4 * a] = w3;
  }
  __syncthreads();
  #pragma unroll
  for (int s = 0; s < 2; ++s) {
    const int idx = t + 256 * s;
    const int c = idx >> 3, g = idx & 7;
    const float4 p0 = *(const float4*)&T[c][8 * g];
    const float4 p1 = *(const float4*)&T[c][8 * g + 4];
    *(uint4*)&xsT[(size_t)(c0 + c) * NNODE + r0 + 8 * g] = pack8(p0, p1);
  }
}

__global__ __launch_bounds__(256) void prep_w(const float* __restrict__ W,
                                              u16* __restrict__ Wb) {
  const int i = (blockIdx.x * 256 + threadIdx.x) * 8;
  const float4 a = *(const float4*)&W[i];
  const float4 b = *(const float4*)&W[i + 4];
  *(uint4*)&Wb[i] = pack8(a, b);
}

// ---------------------------------------------------------------------------
// reduce1: t[e][c] = bf16( (1/(de[e]+eps)) * sum_s tPart[s][e][c] ), S=8
// ---------------------------------------------------------------------------
__global__ __launch_bounds__(256) void reduce1(const float* __restrict__ tPart,
                                               const float* __restrict__ de,
                                               u16* __restrict__ t) {
  const int base = (blockIdx.x * 256 + threadIdx.x) * 8;
  const int e = base >> 8;
  float4 s0 = {0.f, 0.f, 0.f, 0.f}, s1 = {0.f, 0.f, 0.f, 0.f};
  #pragma unroll
  for (int s = 0; s < 8; ++s) {
    const float* p = tPart + (size_t)s * (NEDGE * NCH) + base;
    const float4 a = *(const float4*)p;
    const float4 c = *(const float4*)(p + 4);
    s0.x += a.x; s0.y += a.y; s0.z += a.z; s0.w += a.w;
    s1.x += c.x; s1.y += c.y; s1.z += c.z; s1.w += c.w;
  }
  const float inv = 1.0f / (de[e] + EPSV);
  s0.x *= inv; s0.y *= inv; s0.z *= inv; s0.w *= inv;
  s1.x *= inv; s1.y *= inv; s1.z *= inv; s1.w *= inv;
  *(uint4*)&t[base] = pack8(s0, s1);
}

// ---------------------------------------------------------------------------
// reduce2: out[n][o] = b[o] + rsqrt(dv[n]+eps) * sum_s oPart[s][n][o], S=8
// ---------------------------------------------------------------------------
__global__ __launch_bounds__(256) void reduce2(const float* __restrict__ oPart,
                                               const float* __restrict__ dv,
                                               const float* __restrict__ b,
                                               float* __restrict__ out) {
  const int base = (blockIdx.x * 256 + threadIdx.x) * 8;
  const int n = base >> 8, o0 = base & 255;
  float4 s0 = {0.f, 0.f, 0.f, 0.f}, s1 = {0.f, 0.f, 0.f, 0.f};
  #pragma unroll
  for (int s = 0; s < 8; ++s) {
    const float* p = oPart + (size_t)s * (NNODE * NCH) + base;
    const float4 a = *(const float4*)p;
    const float4 c = *(const float4*)(p + 4);
    s0.x += a.x; s0.y += a.y; s0.z += a.z; s0.w += a.w;
    s1.x += c.x; s1.y += c.y; s1.z += c.z; s1.w += c.w;
  }
  const float sc = rsqrtf(dv[n] + EPSV);
  const float4 b0 = *(const float4*)&b[o0];
  const float4 b1 = *(const float4*)&b[o0 + 4];
  float4 r0, r1;
  r0.x = s0.x * sc + b0.x; r0.y = s0.y * sc + b0.y;
  r0.z = s0.z * sc + b0.z; r0.w = s0.w * sc + b0.w;
  r1.x = s1.x * sc + b1.x; r1.y = s1.y * sc + b1.y;
  r1.z = s1.z * sc + b1.z; r1.w = s1.w * sc + b1.w;
  *(float4*)&out[base] = r0;
  *(float4*)&out[base + 4] = r1;
}

// ---------------------------------------------------------------------------
// staging helpers (XOR-swizzled via pre-swizzled global source, linear LDS)
// ---------------------------------------------------------------------------
template <int ROWS, int NT>
static __device__ __forceinline__ void stage_gl(const u16* __restrict__ base,
                                                int row0, int K, int kt,
                                                u16* lds, int tid) {
  const int w = tid >> 6, l = tid & 63;
  #pragma unroll
  for (int i = 0; i < (ROWS * 8) / NT; ++i) {
    const int slot = i * NT + w * 64 + l;
    const int row = slot >> 3, ch = slot & 7;
    const int sch = ch ^ (row & 7);
    gload16(base + (size_t)(row0 + row) * K + kt + sch * 8,
            lds + (size_t)(i * NT + w * 64) * 8);
  }
}

template <int ROWS, int NT>
static __device__ __forceinline__ void stage_f32(const float* __restrict__ base,
                                                 int row0, int K, int kt,
                                                 u16* lds, int tid) {
  #pragma unroll
  for (int i = 0; i < (ROWS * 8) / NT; ++i) {
    const int idx = i * NT + tid;
    const int row = idx >> 3, ch = idx & 7;
    const size_t g = (size_t)(row0 + row) * K + kt + ch * 8;
    const float4 v0 = *(const float4*)&base[g];
    const float4 v1 = *(const float4*)&base[g + 4];
    *(uint4*)&lds[row * 64 + ((ch ^ (row & 7)) * 8)] = pack8(v0, v1);
  }
}

// ---------------------------------------------------------------------------
// NT GEMM, split-K via plain f32 partial slabs (NO atomics).
// C[m][n] = sum_k A[m][k]*B[n][k], bf16 MFMA 16x16x32.
// ASRC: 0 = A bf16 gload_lds; 1 = A f32 reg-staged (convert in staging)
// EPI : 0 = f32 store to partial slab (Cout + z*pstride); 2 = bf16 store
// ---------------------------------------------------------------------------
template <int BM, int BN, int WM, int WN, int ASRC, int EPI>
__global__ __launch_bounds__(WM * WN * 64, 4) void gemm_nt(
    const void* __restrict__ Aptr, const u16* __restrict__ Bt,
    int K, int KC,
    void* __restrict__ Cout, int ldc, size_t pstride) {
  constexpr int BK = 64;
  constexpr int NT = WM * WN * 64;
  constexpr int WMR = BM / WM, WNR = BN / WN;
  constexpr int FM = WMR / 16, FN = WNR / 16;
  __shared__ u16 lds_a[BM * BK];
  __shared__ u16 lds_b[BN * BK];

  const int tid  = threadIdx.x;
  const int lane = tid & 63;
  const int w    = tid >> 6;
  const int wm   = w / WN, wn = w % WN;
  const int m0   = blockIdx.x * BM;
  const int n0   = blockIdx.y * BN;
  const int k0   = blockIdx.z * KC;

  f32x4 acc[FM][FN];
  #pragma unroll
  for (int fm = 0; fm < FM; ++fm)
    #pragma unroll
    for (int fn = 0; fn < FN; ++fn)
      acc[fm][fn] = (f32x4){0.f, 0.f, 0.f, 0.f};

  for (int kt = k0; kt < k0 + KC; kt += BK) {
    __syncthreads();
    if constexpr (ASRC == 0) {
      stage_gl<BM, NT>((const u16*)Aptr, m0, K, kt, lds_a, tid);
    } else {
      stage_f32<BM, NT>((const float*)Aptr, m0, K, kt, lds_a, tid);
    }
    stage_gl<BN, NT>(Bt, n0, K, kt, lds_b, tid);
    __syncthreads();

    #pragma unroll
    for (int kk = 0; kk < 2; ++kk) {
      bf16x8 af[FM], bfv[FN];
      #pragma unroll
      for (int fm = 0; fm < FM; ++fm) {
        const int row = wm * WMR + fm * 16 + (lane & 15);
        const int ch  = kk * 4 + (lane >> 4);
        af[fm] = *(const bf16x8*)&lds_a[row * BK + ((ch ^ (row & 7)) * 8)];
      }
      #pragma unroll
      for (int fn = 0; fn < FN; ++fn) {
        const int row = wn * WNR + fn * 16 + (lane & 15);
        const int ch  = kk * 4 + (lane >> 4);
        bfv[fn] = *(const bf16x8*)&lds_b[row * BK + ((ch ^ (row & 7)) * 8)];
      }
      #pragma unroll
      for (int fm = 0; fm < FM; ++fm)
        #pragma unroll
        for (int fn = 0; fn < FN; ++fn)
          acc[fm][fn] = __builtin_amdgcn_mfma_f32_16x16x32_bf16(
              af[fm], bfv[fn], acc[fm][fn], 0, 0, 0);
    }
  }

  if constexpr (EPI == 0) {
    float* C = (float*)Cout + (size_t)blockIdx.z * pstride;
    #pragma unroll
    for (int fm = 0; fm < FM; ++fm) {
      const int rowb = m0 + wm * WMR + fm * 16 + ((lane >> 4) << 2);
      #pragma unroll
      for (int fn = 0; fn < FN; ++fn) {
        const int col = n0 + wn * WNR + fn * 16 + (lane & 15);
        #pragma unroll
        for (int r = 0; r < 4; ++r)
          C[(size_t)(rowb + r) * ldc + col] = acc[fm][fn][r];
      }
    }
  } else {
    u16* C = (u16*)Cout;
    #pragma unroll
    for (int fm = 0; fm < FM; ++fm) {
      const int rowb = m0 + wm * WMR + fm * 16 + ((lane >> 4) << 2);
      #pragma unroll
      for (int fn = 0; fn < FN; ++fn) {
        const int col = n0 + wn * WNR + fn * 16 + (lane & 15);
        #pragma unroll
        for (int r = 0; r < 4; ++r)
          C[(size_t)(rowb + r) * ldc + col] = f2bf(acc[fm][fn][r]);
      }
    }
  }
}

// ---------------------------------------------------------------------------
extern "C" void kernel_launch(void* const* d_in, const int* in_sizes, int n_in,
                              void* d_out, int out_size, void* d_ws, size_t ws_size,
                              hipStream_t stream) {
  const float* x = (const float*)d_in[0];   // [8192][256]
  const float* H = (const float*)d_in[1];   // [8192][4096]
  const float* W = (const float*)d_in[2];   // [256][256]
  const float* b = (const float*)d_in[3];   // [256]
  float* out = (float*)d_out;               // [8192][256] f32

  char* ws = (char*)d_ws;
  u16*   HbT   = (u16*)(ws);                        // 64 MiB [E][N] bf16
  u16*   xsT   = (u16*)(ws + 67108864ull);          //  4 MiB [C][N] bf16
  u16*   t     = (u16*)(ws + 71303168ull);          //  2 MiB [E][C] bf16
  u16*   uT    = (u16*)(ws + 73400320ull);          //  2 MiB [O][E] bf16
  u16*   Wb    = (u16*)(ws + 75497472ull);          // 128 KiB
  float* dv    = (float*)(ws + 75628544ull);        // 32 KiB
  float* de    = (float*)(ws + 75661312ull);        // 16 KiB
  float* tPart = (float*)(ws + 75694080ull);        // 32 MiB [8][E][C] f32
  float* oPart = (float*)(ws + 75694080ull);        // 64 MiB [8][N][C] f32 (alias,
                                                    //  tPart dead after reduce1)

  hipMemsetAsync(dv, 0, (NNODE + NEDGE) * sizeof(float), stream);

  prep_h<<<dim3(NNODE / 64, NEDGE / 64), 256, 0, stream>>>(H, HbT, dv, de);
  prep_x<<<dim3(NNODE / 64, NCH / 64), 256, 0, stream>>>(x, dv, xsT);
  prep_w<<<32, 256, 0, stream>>>(W, Wb);

  // GEMM1: tPart[z][e][c] = sum_{k-chunk z} HbT[e][n]*xsT[c][n]  (S=8)
  gemm_nt<128, 128, 2, 2, 0, 0><<<dim3(NEDGE / 128, NCH / 128, 8), 256, 0, stream>>>(
      HbT, xsT, NNODE, NNODE / 8, tPart, NCH, (size_t)NEDGE * NCH);
  // t = bf16(de_inv * sum_z tPart)
  reduce1<<<(NEDGE * NCH) / 2048, 256, 0, stream>>>(tPart, de, t);
  // GEMM-W: uT[o][e] = sum_c Wb[o][c]*t[e][c]
  gemm_nt<128, 128, 2, 2, 0, 2><<<dim3(NCH / 128, NEDGE / 128, 1), 256, 0, stream>>>(
      Wb, t, NCH, NCH, uT, NEDGE, 0);
  // GEMM2: oPart[z][n][o] = sum_{e-chunk z} H[n][e]*uT[o][e]  (S=8, A=f32 H)
  gemm_nt<128, 256, 2, 4, 1, 0><<<dim3(NNODE / 128, 1, 8), 512, 0, stream>>>(
      H, uT, NEDGE, NEDGE / 8, oPart, NCH, (size_t)NNODE * NCH);
  // out = bias + dv_is * sum_z oPart
  reduce2<<<(NNODE * NCH) / 2048, 256, 0, stream>>>(oPart, dv, b, out);
}